// Round 11
// baseline (585.875 us; speedup 1.0000x reference)
//
#include <hip/hip_runtime.h>
#include <math.h>

// ---- problem constants ----
#define TB        256           // threads per block = 4 waves
#define POSB      64            // positions per block (1 per lane, shared by all waves)
#define GROUPS    4             // K-split: wave g scans codes [g*KPG,(g+1)*KPG)
#define KPG       128           // codes per group
#define KB        4             // codes per pass (acc 32 regs; sized to the 56-VGPR pin)
#define NPOS      131072        // B*H*W positions
#define KCODES    512
#define DIM       64
#define HW        4096          // H*W
#define ROWD      17            // float4 per LDS x2 row (68 dwords, R4-proven b128 layout)
#define LOSS_OFF  8388608ull
#define ENC_OFF   8388609ull    // encodings: 67108864 dwords
#define PERP_OFF  75497473ull

__device__ __forceinline__ float tree8(float r0, float r1, float r2, float r3,
                                       float r4, float r5, float r6, float r7) {
    // numpy pairwise combine: ((r0+r1)+(r2+r3)) + ((r4+r5)+(r6+r7))
    return __fadd_rn(__fadd_rn(__fadd_rn(r0, r1), __fadd_rn(r2, r3)),
                     __fadd_rn(__fadd_rn(r4, r5), __fadd_rn(r6, r7)));
}

// Prep: ww[k] = sum(w[k]^2) in numpy pairwise order; zero counts + loss accumulator.
extern "C" __global__ __launch_bounds__(512)
void vq_prep(const float* __restrict__ w, float* __restrict__ ww,
             int* __restrict__ counts, float* __restrict__ lossAcc)
{
    const int k = threadIdx.x;                 // 512 threads
    const float* wk = w + k * DIM;
    float r[8];
    #pragma unroll
    for (int i = 0; i < 8; ++i) {
        #pragma unroll
        for (int j = 0; j < 8; ++j) {
            float v = wk[i * 8 + j];
            float pp = __fmul_rn(v, v);
            r[j] = (i == 0) ? pp : __fadd_rn(r[j], pp);
        }
    }
    ww[k] = tree8(r[0], r[1], r[2], r[3], r[4], r[5], r[6], r[7]);
    counts[k] = 0;
    if (k == 0) *lossAcc = 0.0f;
}

// Main kernel, R11: R10 minus the DS-issue wall.
// R10 diagnosis: 64 ds_read_b32/pass x 64 passes x 32 waves/CU x ~5.8cyc
// = ~317us of DS-pipe time == measured 265us -> DS-throughput-bound on
// narrow reads. Fix: ds_read_b128 (85 B/cyc vs 44) + KB=4 codes/pass
// (halves DS bytes). DS floor ~82us/CU; VALU ~61us/SIMD. Register design
// targets the pinned 56-VGPR budget: acc[4][8]=32 + xc + addr ~= 52.
// One shared x2 copy (64 rows x 17 float4), 7 blocks/CU = 28 waves/CU
// hides the wave-uniform s_load w-stream. Coalesced float4 zero-fill fused.
extern "C" __global__ __launch_bounds__(TB)
void vq_scan(const float* __restrict__ x, const float* __restrict__ w,
             const float* __restrict__ ww, float* __restrict__ out,
             int* __restrict__ counts, float* __restrict__ lossAcc)
{
    __shared__ float4 x2ls[POSB * ROWD];       // 17408 B, 2x values
    __shared__ float  cdist[GROUPS][POSB];     // 1024 B
    __shared__ int    ckidx[GROUPS][POSB];     // 1024 B
    __shared__ int    hcount[KCODES];          // 2048 B

    const int tid = threadIdx.x;
    const int l   = tid & 63;                                  // lane = position slot
    const int g   = __builtin_amdgcn_readfirstlane(tid >> 6);  // wave id, uniform
    const int n   = blockIdx.x * POSB + l;                     // position (64|4096: one b per block)
    const int b   = n >> 12;
    const int hw  = n & 4095;

    hcount[tid]      = 0;
    hcount[tid + TB] = 0;

    // ---- prologue: wave g loads dims [16g,16g+16) of its lane's position
    // (coalesced global) and stores 2x as 4 float4 chunks. One x2 copy/block.
    const float* xp = x + ((size_t)b * DIM) * HW + hw;
    float4* xrow = &x2ls[l * ROWD];
    #pragma unroll
    for (int t = 0; t < 4; ++t) {
        const int c = 4 * g + t;               // chunk index, g uniform
        float v0 = xp[(size_t)(4 * c + 0) * HW];
        float v1 = xp[(size_t)(4 * c + 1) * HW];
        float v2 = xp[(size_t)(4 * c + 2) * HW];
        float v3 = xp[(size_t)(4 * c + 3) * HW];
        float4 ch;
        ch.x = v0 + v0; ch.y = v1 + v1;        // exact doubling
        ch.z = v2 + v2; ch.w = v3 + v3;
        xrow[c] = ch;                          // ds_write_b128
    }
    __syncthreads();                           // full x2 rows + hcount visible

    // ---- A = sum(x^2) from LDS (b128 reads), numpy pairwise_sum(64) order:
    // chunk c -> (i = c>>1, j = (c&1)*4+e), r[j] over i ascending;
    // xe = 0.5f*(2x) is bit-exact x.
    float r[8];
    #pragma unroll
    for (int c = 0; c < 16; ++c) {
        float4 ch = xrow[c];
        const int j = (c & 1) * 4;
        float e0 = 0.5f * ch.x, e1 = 0.5f * ch.y;
        float e2 = 0.5f * ch.z, e3 = 0.5f * ch.w;
        float p0 = __fmul_rn(e0, e0), p1 = __fmul_rn(e1, e1);
        float p2 = __fmul_rn(e2, e2), p3 = __fmul_rn(e3, e3);
        if (c < 2) { r[j] = p0; r[j+1] = p1; r[j+2] = p2; r[j+3] = p3; }
        else { r[j]   = __fadd_rn(r[j],   p0); r[j+1] = __fadd_rn(r[j+1], p1);
               r[j+2] = __fadd_rn(r[j+2], p2); r[j+3] = __fadd_rn(r[j+3], p3); }
    }
    const float A = tree8(r[0], r[1], r[2], r[3], r[4], r[5], r[6], r[7]);

    // ---- scan my 128-code group, 4 codes per pass; fused coalesced zero-fill.
    // Tile = POSB*KCODES = 32768 dwords at T0 (T0%4==1): dwords 3+4m aligned;
    // m=8191 would cross the tile edge -> written as edge dword below.
    float best  = INFINITY;
    int   bestk = 0;
    const size_t T0 = ENC_OFF + (size_t)blockIdx.x * (POSB * KCODES);
    float4* zs4 = reinterpret_cast<float4*>(out + T0 + 3);
    const float4 zero4 = make_float4(0.0f, 0.0f, 0.0f, 0.0f);

    for (int p = 0; p < KPG / KB; ++p) {       // 32 passes
        const int k0 = g * KPG + p * KB;       // wave-uniform -> s_load path
        const float* w0 = w + (size_t)k0 * DIM;
        float s[KB][8];
        #pragma unroll
        for (int c = 0; c < 16; ++c) {
            const int j = (c & 1) * 4;
            float4 xc = xrow[c];               // one ds_read_b128 feeds 16 FMAs
            #pragma unroll
            for (int kk = 0; kk < KB; ++kk) {
                const float* wc = w0 + kk * DIM + 4 * c;
                if (c < 2) {
                    s[kk][j]   = __fmul_rn(xc.x, wc[0]);   // == fmaf(a,b,0)
                    s[kk][j+1] = __fmul_rn(xc.y, wc[1]);
                    s[kk][j+2] = __fmul_rn(xc.z, wc[2]);
                    s[kk][j+3] = __fmul_rn(xc.w, wc[3]);
                } else {
                    s[kk][j]   = __fmaf_rn(xc.x, wc[0], s[kk][j]);
                    s[kk][j+1] = __fmaf_rn(xc.y, wc[1], s[kk][j+1]);
                    s[kk][j+2] = __fmaf_rn(xc.z, wc[2], s[kk][j+2]);
                    s[kk][j+3] = __fmaf_rn(xc.w, wc[3], s[kk][j+3]);
                }
            }
        }
        #pragma unroll
        for (int kk = 0; kk < KB; ++kk) {      // ascending k: ties keep first
            float dot  = tree8(s[kk][0], s[kk][1], s[kk][2], s[kk][3],
                               s[kk][4], s[kk][5], s[kk][6], s[kk][7]);
            float dist = __fadd_rn(__fadd_rn(A, ww[k0 + kk]), -dot);
            if (dist < best) { best = dist; bestk = k0 + kk; }
        }

        const int m = p * TB + tid;            // [0, 8192): 32 passes x 256 thr
        if (m < 8191) zs4[m] = zero4;          // coalesced; drains behind FMAs
    }
    cdist[g][l] = best;
    ckidx[g][l] = bestk;

    // edge dwords of the tile (not covered by the float4 sweep)
    if (tid < 3)  out[T0 + tid]   = 0.0f;      // d = 0,1,2
    if (tid == 3) out[T0 + 32767] = 0.0f;      // d = 32767

    __syncthreads();   // zero stores drained (vmcnt(0) at barrier); candidates visible

    // ---- merge 4 candidates (ascending g = ascending k: ties keep first) ----
    float fb = cdist[0][l];
    int   fk = ckidx[0][l];
    #pragma unroll
    for (int gg = 1; gg < GROUPS; ++gg) {
        float dg = cdist[gg][l];
        int   kg = ckidx[gg][l];
        if (dg < fb) { fb = dg; fk = kg; }
    }

    // ---- epilogue: wave 0 only ----
    if (g == 0) {
        out[ENC_OFF + (size_t)n * KCODES + fk] = 1.0f;   // one-hot after tile zeros
        atomicAdd(&hcount[fk], 1);

        const float4* wrow = reinterpret_cast<const float4*>(w + (size_t)fk * DIM);
        float* qo = out + ((size_t)b * DIM) * HW + hw;
        float sse = 0.0f;
        #pragma unroll
        for (int c = 0; c < 16; ++c) {
            float4 q  = wrow[c];
            float4 xc = xrow[c];               // 2x, so 0.5f* is exact
            qo[(size_t)(4 * c + 0) * HW] = q.x;
            qo[(size_t)(4 * c + 1) * HW] = q.y;
            qo[(size_t)(4 * c + 2) * HW] = q.z;
            qo[(size_t)(4 * c + 3) * HW] = q.w;
            float e0 = q.x - 0.5f * xc.x; sse = __fmaf_rn(e0, e0, sse);
            float e1 = q.y - 0.5f * xc.y; sse = __fmaf_rn(e1, e1, sse);
            float e2 = q.z - 0.5f * xc.z; sse = __fmaf_rn(e2, e2, sse);
            float e3 = q.w - 0.5f * xc.w; sse = __fmaf_rn(e3, e3, sse);
        }
        // wave-level SSE reduction (64 lanes)
        #pragma unroll
        for (int off = 32; off > 0; off >>= 1) sse += __shfl_down(sse, off);
        if (l == 0) atomicAdd(lossAcc, sse);
    }

    __syncthreads();   // wave 0's hcount atomics done

    // histogram drain
    {
        int c0 = hcount[tid];       if (c0) atomicAdd(&counts[tid], c0);
        int c1 = hcount[tid + TB];  if (c1) atomicAdd(&counts[tid + TB], c1);
    }
}

// Finalize: loss scalar + perplexity from histogram.
extern "C" __global__ __launch_bounds__(512)
void vq_finalize(const int* __restrict__ counts, const float* __restrict__ lossAcc,
                 float* __restrict__ out)
{
    __shared__ double sred[KCODES];
    const int t = threadIdx.x;                 // 512 threads
    double p = (double)counts[t] * (1.0 / (double)NPOS);
    sred[t] = -p * log(p + 1e-10);
    __syncthreads();
    for (int s = KCODES / 2; s > 0; s >>= 1) {
        if (t < s) sred[t] += sred[t + s];
        __syncthreads();
    }
    if (t == 0) {
        out[PERP_OFF] = (float)exp(sred[0]);
        out[LOSS_OFF] = 1.25f * (lossAcc[0] / 8388608.0f);
    }
}

extern "C" void kernel_launch(void* const* d_in, const int* in_sizes, int n_in,
                              void* d_out, int out_size, void* d_ws, size_t ws_size,
                              hipStream_t stream)
{
    const float* x = (const float*)d_in[0];    // [32,64,64,64] fp32
    const float* w = (const float*)d_in[1];    // [512,64] fp32
    float* out = (float*)d_out;

    float* ww      = (float*)d_ws;                         // 512 floats
    int*   counts  = (int*)((char*)d_ws + 2048);           // 512 ints
    float* lossAcc = (float*)((char*)d_ws + 4096);         // 1 float

    vq_prep<<<1, 512, 0, stream>>>(w, ww, counts, lossAcc);
    vq_scan<<<NPOS / POSB, TB, 0, stream>>>(x, w, ww, out, counts, lossAcc);
    vq_finalize<<<1, 512, 0, stream>>>(counts, lossAcc, out);
}